// Round 17
// baseline (860.744 us; speedup 1.0000x reference)
//
#include <hip/hip_runtime.h>
#include <math.h>

#define SEQL 1024
#define NB 8
#define DMOD 512

// ---------- reduction helpers (256-thread blocks, 4 waves) ----------
__device__ __forceinline__ float blk_sum4(float v, volatile float* sb) {
#pragma unroll
  for (int off = 32; off; off >>= 1) v += __shfl_xor(v, off, 64);
  int lid = threadIdx.x & 63, wid = threadIdx.x >> 6;
  if (lid == 0) sb[wid] = v;
  __syncthreads();
  float t = sb[0] + sb[1] + sb[2] + sb[3];
  __syncthreads();
  return t;
}
__device__ __forceinline__ float blk_max4(float v, volatile float* sb) {
#pragma unroll
  for (int off = 32; off; off >>= 1) v = fmaxf(v, __shfl_xor(v, off, 64));
  int lid = threadIdx.x & 63, wid = threadIdx.x >> 6;
  if (lid == 0) sb[wid] = v;
  __syncthreads();
  float t = fmaxf(fmaxf(sb[0], sb[1]), fmaxf(sb[2], sb[3]));
  __syncthreads();
  return t;
}

// ---------- generic f32 GEMM, 64x64 tile, BK=32 (half the barriers) ----------
// Requires K % 32 == 0 (all call sites: 512/256/128). M/N guarded.
__global__ __launch_bounds__(256) void gemm_f32(
    const float* __restrict__ A, long aStr,
    const float* __restrict__ B, long bStr,
    const float* __restrict__ Dm, long dStr,
    float* __restrict__ C, long cStr, long cChunkStr,
    int M, int N, int K, int lda, int ldb, int ldd, int ldc,
    float alpha, float beta, int kchunks) {
  __shared__ float As[2][32][68];
  __shared__ float Bs[2][32][64];
  const int zz = blockIdx.z;
  const int zb = zz / kchunks, kc = zz % kchunks;
  A += (long)zb * aStr + (long)kc * K;
  B += (long)zb * bStr + (long)kc * K * ldb;
  Dm += (long)zb * dStr;
  C += (long)zb * cStr + (long)kc * cChunkStr;
  const int tid = threadIdx.x;
  const int m0 = blockIdx.y * 64, n0 = blockIdx.x * 64;
  const int tx = tid & 15, ty = tid >> 4;
  const int arow = tid >> 2, acol = (tid & 3) << 3;   // 64 rows x 8 cols
  const int brow = tid >> 4, bcol = (tid & 15) << 2;  // rows brow,brow+16 x 4 cols
  const bool aOk = (m0 + arow < M);
  const float* Aptr = A + (long)(m0 + arow) * lda + acol;
  const float* Bptr = B + (long)brow * ldb;
  const int bc = n0 + bcol;
  const int kIters = K >> 5;
  float acc[4][4] = {};

  auto loadBrow = [&](const float* Bk) {
    float4 r;
    if (bc + 3 < N) r = *(const float4*)(Bk + bc);
    else {
      r.x = (bc + 0 < N) ? Bk[bc + 0] : 0.f;
      r.y = (bc + 1 < N) ? Bk[bc + 1] : 0.f;
      r.z = (bc + 2 < N) ? Bk[bc + 2] : 0.f;
      r.w = (bc + 3 < N) ? Bk[bc + 3] : 0.f;
    }
    return r;
  };

  float4 av0 = make_float4(0.f, 0.f, 0.f, 0.f), av1 = av0;
  if (aOk) {
    av0 = *(const float4*)(Aptr);
    av1 = *(const float4*)(Aptr + 4);
  }
  float4 bv0 = loadBrow(Bptr);
  float4 bv1 = loadBrow(Bptr + 16 * ldb);
  As[0][acol + 0][arow] = av0.x; As[0][acol + 1][arow] = av0.y;
  As[0][acol + 2][arow] = av0.z; As[0][acol + 3][arow] = av0.w;
  As[0][acol + 4][arow] = av1.x; As[0][acol + 5][arow] = av1.y;
  As[0][acol + 6][arow] = av1.z; As[0][acol + 7][arow] = av1.w;
  *(float4*)&Bs[0][brow][bcol] = bv0;
  *(float4*)&Bs[0][brow + 16][bcol] = bv1;

  for (int it = 0; it < kIters; ++it) {
    const int cur = it & 1;
    __syncthreads();
    const bool more = (it + 1 < kIters);
    if (more) {
      if (aOk) {
        av0 = *(const float4*)(Aptr + (it + 1) * 32);
        av1 = *(const float4*)(Aptr + (it + 1) * 32 + 4);
      }
      const float* Bk = Bptr + (long)(it + 1) * 32 * ldb;
      bv0 = loadBrow(Bk);
      bv1 = loadBrow(Bk + 16 * ldb);
    }
#pragma unroll
    for (int kk = 0; kk < 32; ++kk) {
      float4 aq = *(const float4*)&As[cur][kk][ty << 2];
      float4 bq = *(const float4*)&Bs[cur][kk][tx << 2];
      float aa[4] = {aq.x, aq.y, aq.z, aq.w};
      float bb[4] = {bq.x, bq.y, bq.z, bq.w};
#pragma unroll
      for (int i = 0; i < 4; ++i)
#pragma unroll
        for (int j = 0; j < 4; ++j) acc[i][j] = fmaf(aa[i], bb[j], acc[i][j]);
    }
    if (more) {
      const int nxt = cur ^ 1;
      As[nxt][acol + 0][arow] = av0.x; As[nxt][acol + 1][arow] = av0.y;
      As[nxt][acol + 2][arow] = av0.z; As[nxt][acol + 3][arow] = av0.w;
      As[nxt][acol + 4][arow] = av1.x; As[nxt][acol + 5][arow] = av1.y;
      As[nxt][acol + 6][arow] = av1.z; As[nxt][acol + 7][arow] = av1.w;
      *(float4*)&Bs[nxt][brow][bcol] = bv0;
      *(float4*)&Bs[nxt][brow + 16][bcol] = bv1;
    }
  }
#pragma unroll
  for (int i = 0; i < 4; ++i) {
    int row = m0 + (ty << 2) + i;
    if (row >= M) continue;
#pragma unroll
    for (int j = 0; j < 4; ++j) {
      int col = n0 + (tx << 2) + j;
      if (col >= N) continue;
      float v = alpha * acc[i][j];
      if (beta != 0.f) v += beta * Dm[(long)row * ldd + col];
      C[(long)row * ldc + col] = v;
    }
  }
}

// ---------- fused conv + SiLU + x-proj + dt-proj (4 tokens/wave, pw in LDS) ----------
__global__ __launch_bounds__(256) void convproj(
    const float* __restrict__ xr, const float* __restrict__ cw,
    const float* __restrict__ cb, const float* __restrict__ pw,
    const float* __restrict__ dw, const float* __restrict__ db,
    float* __restrict__ Bm, float* __restrict__ Cm,
    float* __restrict__ xpT, float* __restrict__ dlT, float* __restrict__ sigT) {
  __shared__ float sWp[8448];      // per-dir x-proj weights (33 KB)
  int dir = blockIdx.y;
  int L = blockIdx.x;              // 0..511
  int r = L & 7, q = L >> 3;       // XCD class r = batch b
  int wv = threadIdx.x >> 6, e = threadIdx.x & 63;
  int b = r;
  int t0 = q * 16 + wv * 4;        // 4 consecutive tokens per wave
  long tokbase = (long)b * 1024;
  const float* x0p = xr + (long)dir * 1048576;
  const float* wp = pw + dir * 8448;
  for (int i = threadIdx.x; i < 8448; i += 256) sWp[i] = wp[i];
  int base = dir ? t0 : t0 - 2;
  float X[6];
#pragma unroll
  for (int j = 0; j < 6; ++j) {
    int tt = base + j;
    X[j] = (tt >= 0 && tt <= 1023) ? x0p[(tokbase + tt) * 128 + e] : 0.f;
  }
  const float* w = cw + dir * 192;
  float w0 = w[e * 3 + 0], w1 = w[e * 3 + 1], w2 = w[e * 3 + 2];
  float wLo = dir ? w2 : w0;
  float wHi = dir ? w0 : w2;
  float cbv = cb[dir * 64 + e];
  float xpv[4], sg[4];
#pragma unroll
  for (int i = 0; i < 4; ++i) {
    float acc = cbv + wLo * X[i] + w1 * X[i + 1] + wHi * X[i + 2];
    xpv[i] = acc / (1.f + __expf(-acc));
    float res = x0p[(tokbase + t0 + i) * 128 + 64 + e];
    sg[i] = 1.f / (1.f + __expf(-res));
  }
  __syncthreads();
  float aB[4] = {}, aC[4] = {}, aD[4] = {};
  for (int k = 0; k < 64; ++k) {
    const float* wr = sWp + k * 132;
    float wB = wr[4 + e], wC = wr[68 + e], wD = wr[e & 3];
#pragma unroll
    for (int i = 0; i < 4; ++i) {
      float xk = __shfl(xpv[i], k, 64);
      aB[i] = fmaf(xk, wB, aB[i]);
      aC[i] = fmaf(xk, wC, aC[i]);
      aD[i] = fmaf(xk, wD, aD[i]);
    }
  }
  long ob = (long)dir * 524288 + (tokbase + t0) * 64 + e;
#pragma unroll
  for (int i = 0; i < 4; ++i) {
    Bm[ob + (long)i * 64] = aB[i];
    Cm[ob + (long)i * 64] = aC[i];
  }
  const float* dwp = dw + dir * 256;
  float dbv = db[dir * 64 + e];
  float dl[4];
#pragma unroll
  for (int i = 0; i < 4; ++i) {
    float dv = dbv;
#pragma unroll
    for (int rr = 0; rr < 4; ++rr) dv = fmaf(__shfl(aD[i], rr, 64), dwp[rr * 64 + e], dv);
    dl[i] = fmaxf(dv, 0.f) + log1pf(__expf(-fabsf(dv)));
  }
  long tb2 = (long)dir * 524288 + (long)b * 65536 + (long)e * 1024 + t0;
  *(float4*)&xpT[tb2] = make_float4(xpv[0], xpv[1], xpv[2], xpv[3]);
  *(float4*)&dlT[tb2] = make_float4(dl[0], dl[1], dl[2], dl[3]);
  *(float4*)&sigT[tb2] = make_float4(sg[0], sg[1], sg[2], sg[3]);
}

// ---------- XCD-aware remap, 4 waves/block (scan_p1) ----------
__device__ __forceinline__ void remap4w(int wv, int& d, int& b, int& dir, int& c) {
  int L = blockIdx.x + 64 * (blockIdx.y + 8 * blockIdx.z);  // grid (64,8,8) = 4096
  int r = L & 7, s = L >> 3;
  int u = s * 4 + wv;            // 0..2047 within class r
  d = u & 63;
  int T = (u >> 6) * 8 + r;      // 0..255
  b = T >> 5;
  dir = (T >> 4) & 1;
  c = T & 15;
}

// ---------- XCD-aware remap, 1-wave blocks (scan_p3) ----------
__device__ __forceinline__ void scan_remap(int& d, int& b, int& dir, int& c) {
  int L = blockIdx.x + 64 * (blockIdx.y + 8 * blockIdx.z);  // grid (64,8,32)
  int r = L & 7, q = L >> 3;
  d = q & 63;
  int T = (q >> 6) * 8 + r;  // 0..255
  b = T >> 5;
  dir = (T >> 4) & 1;
  c = T & 15;
}

// ---------- chunked parallel selective scan ----------
// p1: 4 waves/block, register-prefetched B sub-blocks
__global__ __launch_bounds__(256) void scan_p1(
    const float* __restrict__ dlT, const float* __restrict__ xpT,
    const float* __restrict__ Bm, const float* __restrict__ Alog,
    float* __restrict__ Aprod, float* __restrict__ Send) {
  int wv = threadIdx.x >> 6, n = threadIdx.x & 63;
  int d, b, dir, c;
  remap4w(wv, d, b, dir, c);
  long tbase = (long)dir * 524288 + (long)b * 65536 + (long)d * 1024;
  int t0 = c * 64;
  float a_dn = -__expf(Alog[dir * 4096 + d * 64 + n]);
  int tg0 = dir ? (1023 - t0) : t0;
  long bstep = dir ? -64 : 64;
  const float* bp = Bm + (long)dir * 524288 + ((long)b * 1024 + tg0) * 64 + n;
  const float* dlrow = dlT + tbase;
  const float* xprow = xpT + tbase;
  float s = 0.f, ap0 = 1.f, ap1 = 1.f;
  float bcur[16];
#pragma unroll
  for (int k = 0; k < 16; ++k) bcur[k] = bp[(long)k * bstep];
  bp += 16 * bstep;
  for (int sb = 0; sb < 4; ++sb) {
    float sa[16], su[16];
#pragma unroll
    for (int k = 0; k < 16; ++k) {
      int tl = t0 + sb * 16 + k;
      int tg = dir ? 1023 - tl : tl;
      float dv = dlrow[tg];
      sa[k] = dv;
      su[k] = dv * xprow[tg];
    }
    float bnxt[16];
    if (sb < 3) {
#pragma unroll
      for (int k = 0; k < 16; ++k) bnxt[k] = bp[(long)k * bstep];
      bp += 16 * bstep;
    }
#pragma unroll
    for (int k = 0; k < 16; ++k) {
      float a = __expf(sa[k] * a_dn);
      if (k & 1) ap1 *= a; else ap0 *= a;
      s = fmaf(a, s, su[k] * bcur[k]);
    }
    if (sb < 3) {
#pragma unroll
      for (int k = 0; k < 16; ++k) bcur[k] = bnxt[k];
    }
  }
  long sidx = ((long)((dir * 8 + b) * 64 + d)) * 1024 + c * 64 + n;
  Aprod[sidx] = ap0 * ap1;
  Send[sidx] = s;
}

__global__ __launch_bounds__(64) void scan_p2(
    const float* __restrict__ Aprod, const float* __restrict__ Send,
    float* __restrict__ Sin) {
  int d = blockIdx.x, b = blockIdx.y, dir = blockIdx.z;
  int n = threadIdx.x;
  long base = ((long)((dir * 8 + b) * 64 + d)) * 1024;
  float apv[16], sev[16];
#pragma unroll
  for (int c = 0; c < 16; ++c) {
    apv[c] = Aprod[base + c * 64 + n];
    sev[c] = Send[base + c * 64 + n];
  }
  float s = 0.f;
#pragma unroll
  for (int c = 0; c < 16; ++c) {
    Sin[base + c * 64 + n] = s;
    s = fmaf(apv[c], s, sev[c]);
  }
}

// p3: 1-wave blocks + register-prefetched B/C
__global__ __launch_bounds__(64) void scan_p3(
    const float* __restrict__ dlT, const float* __restrict__ xpT,
    const float* __restrict__ sigT, const float* __restrict__ Bm,
    const float* __restrict__ Cm, const float* __restrict__ Alog,
    const float* __restrict__ Dp, const float* __restrict__ Sin,
    float* __restrict__ ycat) {
  __shared__ float sP[16 * 65];
  int d, b, dir, c;
  scan_remap(d, b, dir, c);
  int n = threadIdx.x;
  long tbase = (long)dir * 524288 + (long)b * 65536 + (long)d * 1024;
  int t0 = c * 64;
  int tln = t0 + n;
  int tgn = dir ? 1023 - tln : tln;
  float xp_l = xpT[tbase + tgn];
  float sg_l = sigT[tbase + tgn];
  float a_dn = -__expf(Alog[dir * 4096 + d * 64 + n]);
  float dpd = Dp[dir * 64 + d];
  int tg0 = dir ? (1023 - t0) : t0;
  long bstep = dir ? -64 : 64;
  long boff = (long)dir * 524288 + ((long)b * 1024 + tg0) * 64 + n;
  const float* bp = Bm + boff;
  const float* cp = Cm + boff;
  long sidx = ((long)((dir * 8 + b) * 64 + d)) * 1024 + c * 64 + n;
  float s = Sin[sidx];
  int r4 = n >> 2, q4 = n & 3;
  const float* dlrow = dlT + tbase;
  const float* xprow = xpT + tbase;
  float bcur[16], ccur[16];
#pragma unroll
  for (int k = 0; k < 16; ++k) {
    bcur[k] = bp[(long)k * bstep];
    ccur[k] = cp[(long)k * bstep];
  }
  bp += 16 * bstep; cp += 16 * bstep;
  for (int ph = 0; ph < 4; ++ph) {
    float sa[16], su[16];
#pragma unroll
    for (int k = 0; k < 16; ++k) {
      int tl = t0 + ph * 16 + k;
      int tg = dir ? 1023 - tl : tl;
      float dv = dlrow[tg];
      sa[k] = dv;
      su[k] = dv * xprow[tg];
    }
    float bnxt[16], cnxt[16];
    if (ph < 3) {
#pragma unroll
      for (int k = 0; k < 16; ++k) {
        bnxt[k] = bp[(long)k * bstep];
        cnxt[k] = cp[(long)k * bstep];
      }
      bp += 16 * bstep; cp += 16 * bstep;
    }
#pragma unroll
    for (int k = 0; k < 16; ++k) {
      float a = __expf(sa[k] * a_dn);
      s = fmaf(a, s, su[k] * bcur[k]);
      sP[k * 65 + n] = s * ccur[k];
    }
    __syncthreads();
    float p = 0.f;
#pragma unroll
    for (int k = 0; k < 16; ++k) p += sP[r4 * 65 + q4 * 16 + k];
    p += __shfl_xor(p, 1, 64);
    p += __shfl_xor(p, 2, 64);
    int stl = ph * 16 + r4;
    float xpv_r = __shfl(xp_l, stl, 64);
    float sgv = __shfl(sg_l, stl, 64);
    if (q4 == 0) {
      int tl = t0 + stl;
      int tg = dir ? 1023 - tl : tl;
      ycat[((long)b * 1024 + tg) * 128 + dir * 64 + d] = (p + xpv_r * dpd) * sgv;
    }
    __syncthreads();
    if (ph < 3) {
#pragma unroll
      for (int k = 0; k < 16; ++k) { bcur[k] = bnxt[k]; ccur[k] = cnxt[k]; }
    }
  }
}

// ---------- fused LN1 + FFN(512->32->512) + LN2, 4 tokens per block ----------
__global__ __launch_bounds__(256) void ln_ffn_ln(
    float* __restrict__ x, const float* __restrict__ g1, const float* __restrict__ b1v,
    const float* __restrict__ w1, const float* __restrict__ bb1,
    const float* __restrict__ w2, const float* __restrict__ bb2,
    const float* __restrict__ g2, const float* __restrict__ b2v) {
  __shared__ float ybuf[4][512];
  __shared__ float rbuf[4][256];
  __shared__ float zbuf[4][32];
  __shared__ float red4[32];
  int tid = threadIdx.x;
  int lid = tid & 63, wid = tid >> 6;
  float* row0 = x + (long)blockIdx.x * 2048;
  float a[4], bb[4], s[4], q[4];
#pragma unroll
  for (int t = 0; t < 4; ++t) {
    a[t] = row0[t * 512 + tid];
    bb[t] = row0[t * 512 + tid + 256];
    s[t] = a[t] + bb[t];
    q[t] = a[t] * a[t] + bb[t] * bb[t];
  }
#pragma unroll
  for (int off = 32; off; off >>= 1) {
#pragma unroll
    for (int t = 0; t < 4; ++t) {
      s[t] += __shfl_xor(s[t], off, 64);
      q[t] += __shfl_xor(q[t], off, 64);
    }
  }
  if (lid == 0) {
#pragma unroll
    for (int t = 0; t < 4; ++t) {
      red4[wid * 8 + t] = s[t];
      red4[wid * 8 + 4 + t] = q[t];
    }
  }
  __syncthreads();
  float g1a = g1[tid], g1b = g1[tid + 256];
  float b1a = b1v[tid], b1b = b1v[tid + 256];
  float ya[4], yb[4];
#pragma unroll
  for (int t = 0; t < 4; ++t) {
    float S = red4[t] + red4[8 + t] + red4[16 + t] + red4[24 + t];
    float Q = red4[4 + t] + red4[12 + t] + red4[20 + t] + red4[28 + t];
    float mu = S * (1.f / 512.f);
    float rs = 1.f / sqrtf(Q * (1.f / 512.f) - mu * mu + 1e-5f);
    ya[t] = (a[t] - mu) * rs * g1a + b1a;
    yb[t] = (bb[t] - mu) * rs * g1b + b1b;
    ybuf[t][tid] = ya[t];
    ybuf[t][tid + 256] = yb[t];
  }
  __syncthreads();
  int u = tid & 31, seg = tid >> 5;
  int k0 = seg * 64;
  float p[4] = {};
#pragma unroll
  for (int k = 0; k < 64; k += 4) {
    float w1v0 = w1[(k0 + k + 0) * 32 + u];
    float w1v1 = w1[(k0 + k + 1) * 32 + u];
    float w1v2 = w1[(k0 + k + 2) * 32 + u];
    float w1v3 = w1[(k0 + k + 3) * 32 + u];
#pragma unroll
    for (int t = 0; t < 4; ++t) {
      float4 yv = *(const float4*)&ybuf[t][k0 + k];
      p[t] = fmaf(yv.w, w1v3, fmaf(yv.z, w1v2, fmaf(yv.y, w1v1, fmaf(yv.x, w1v0, p[t]))));
    }
  }
#pragma unroll
  for (int t = 0; t < 4; ++t) rbuf[t][seg * 32 + u] = p[t];
  __syncthreads();
  if (tid < 128) {
    int t = tid >> 5, uu = tid & 31;
    float zv = bb1[uu];
#pragma unroll
    for (int sg = 0; sg < 8; ++sg) zv += rbuf[t][sg * 32 + uu];
    zbuf[t][uu] = fmaxf(zv, 0.f);
  }
  __syncthreads();
  float bb2a = bb2[tid], bb2b = bb2[tid + 256];
  float ha[4], hb[4];
#pragma unroll
  for (int t = 0; t < 4; ++t) { ha[t] = ya[t] + bb2a; hb[t] = yb[t] + bb2b; }
#pragma unroll
  for (int uu = 0; uu < 32; ++uu) {
    float wa = w2[uu * 512 + tid], wb = w2[uu * 512 + tid + 256];
#pragma unroll
    for (int t = 0; t < 4; ++t) {
      float zv = zbuf[t][uu];
      ha[t] = fmaf(zv, wa, ha[t]);
      hb[t] = fmaf(zv, wb, hb[t]);
    }
  }
#pragma unroll
  for (int t = 0; t < 4; ++t) {
    s[t] = ha[t] + hb[t];
    q[t] = ha[t] * ha[t] + hb[t] * hb[t];
  }
#pragma unroll
  for (int off = 32; off; off >>= 1) {
#pragma unroll
    for (int t = 0; t < 4; ++t) {
      s[t] += __shfl_xor(s[t], off, 64);
      q[t] += __shfl_xor(q[t], off, 64);
    }
  }
  __syncthreads();
  if (lid == 0) {
#pragma unroll
    for (int t = 0; t < 4; ++t) {
      red4[wid * 8 + t] = s[t];
      red4[wid * 8 + 4 + t] = q[t];
    }
  }
  __syncthreads();
  float g2a = g2[tid], g2b = g2[tid + 256];
  float b2a = b2v[tid], b2b = b2v[tid + 256];
#pragma unroll
  for (int t = 0; t < 4; ++t) {
    float S = red4[t] + red4[8 + t] + red4[16 + t] + red4[24 + t];
    float Q = red4[4 + t] + red4[12 + t] + red4[20 + t] + red4[28 + t];
    float mu = S * (1.f / 512.f);
    float rs = 1.f / sqrtf(Q * (1.f / 512.f) - mu * mu + 1e-5f);
    row0[t * 512 + tid] = (ha[t] - mu) * rs * g2a + b2a;
    row0[t * 512 + tid + 256] = (hb[t] - mu) * rs * g2b + b2b;
  }
}

// ---------- MAGAC: Q/K projections ----------
__global__ __launch_bounds__(64) void qk_kernel(
    const float* __restrict__ e, const float* __restrict__ Wq,
    const float* __restrict__ Wk, float* __restrict__ Qb, float* __restrict__ Kb) {
  int n = blockIdx.x, j = threadIdx.x;
  __shared__ float en[10];
  if (j < 10) en[j] = e[n * 10 + j];
  __syncthreads();
  if (j < 40) {
    float q = 0.f, k = 0.f;
#pragma unroll
    for (int dd = 0; dd < 10; ++dd) {
      q = fmaf(en[dd], Wq[dd * 40 + j], q);
      k = fmaf(en[dd], Wk[dd * 40 + j], k);
    }
    Qb[n * 40 + j] = q;
    Kb[n * 40 + j] = k;
  }
}

// ---------- MAGAC: A_eff row (dual softmax) ----------
__global__ __launch_bounds__(256) void aeff_kernel(
    const float* __restrict__ e, const float* __restrict__ Qb,
    const float* __restrict__ Kb, const float* __restrict__ psi_p,
    const float* __restrict__ alpha_p, float* __restrict__ Aef) {
  int n = blockIdx.x, h = blockIdx.y, tid = threadIdx.x;
  __shared__ float s_at[512];
  __shared__ float s_bs[512];
  __shared__ float qn[10];
  __shared__ float en[10];
  __shared__ float red[4];
  if (tid < 10) { qn[tid] = Qb[n * 40 + h * 10 + tid]; en[tid] = e[n * 10 + tid]; }
  __syncthreads();
  float psi = psi_p[0];
  float alpha = 1.f / (1.f + __expf(-alpha_p[0]));
  const float isq = 0.3162277660168379f;
  for (int m = tid; m < 512; m += 256) {
    float sc = 0.f, d2 = 0.f;
#pragma unroll
    for (int dd = 0; dd < 10; ++dd) {
      sc = fmaf(qn[dd], Kb[m * 40 + h * 10 + dd], sc);
      float df = en[dd] - e[m * 10 + dd];
      d2 = fmaf(df, df, d2);
    }
    s_at[m] = sc * isq;
    s_bs[m] = __expf(-psi * d2);
  }
  __syncthreads();
  float m1 = -1e30f, m2 = -1e30f;
  for (int m = tid; m < 512; m += 256) { m1 = fmaxf(m1, s_at[m]); m2 = fmaxf(m2, s_bs[m]); }
  m1 = blk_max4(m1, red);
  m2 = blk_max4(m2, red);
  float e1 = 0.f, e2 = 0.f;
  for (int m = tid; m < 512; m += 256) {
    float a = __expf(s_at[m] - m1); s_at[m] = a; e1 += a;
    float bq = __expf(s_bs[m] - m2); s_bs[m] = bq; e2 += bq;
  }
  e1 = blk_sum4(e1, red);
  e2 = blk_sum4(e2, red);
  float r1 = (1.f - alpha) / e1, r2 = alpha / e2;
  float* outp = Aef + (long)h * 262144 + (long)n * 512;
  for (int m = tid; m < 512; m += 256) outp[m] = r2 * s_bs[m] + r1 * s_at[m];
}

// ---------- sum Dbuf K-partials + transpose into Horner operand layouts ----------
__global__ void xpose_kernel(const float* __restrict__ DbufP,
                             float* __restrict__ X3, float* __restrict__ X2s,
                             float* __restrict__ X13, float* __restrict__ X02) {
  int idx = blockIdx.x * 256 + threadIdx.x;  // 163840
  if (idx >= 163840) return;
  int c = idx % 80;
  int m = (idx / 80) % 512;
  int h = idx / 40960;
  int d = c >> 3, b = c & 7;
  long base = (long)(b * 160 + h * 40 + d * 4) * 512 + m;
  float k0 = 0.f, k1 = 0.f, k2 = 0.f, k3 = 0.f;
#pragma unroll
  for (int p = 0; p < 4; ++p) {
    const float* Dp_ = DbufP + (long)p * 655360;
    k0 += Dp_[base];
    k1 += Dp_[base + 512];
    k2 += Dp_[base + 1024];
    k3 += Dp_[base + 1536];
  }
  X3[idx] = k3;
  X2s[idx] = k2;
  X13[idx] = k1 - 3.f * k3;
  X02[idx] = k0 - k2;
}

// ---------- final contraction ----------
__global__ void outh_kernel(const float* __restrict__ e, const float* __restrict__ fb,
                            const float* __restrict__ Zt, const float* __restrict__ hm,
                            float* __restrict__ g) {
  int idx = blockIdx.x * 256 + threadIdx.x;  // 4096
  if (idx >= 4096) return;
  int n = idx & 511, b = idx >> 9;
  float h0 = hm[0], h1 = hm[1], h2 = hm[2], h3 = hm[3];
  float mx = fmaxf(fmaxf(h0, h1), fmaxf(h2, h3));
  float x0 = __expf(h0 - mx), x1 = __expf(h1 - mx), x2 = __expf(h2 - mx), x3 = __expf(h3 - mx);
  float es = x0 + x1 + x2 + x3;
  float mixv[4] = {x0 / es, x1 / es, x2 / es, x3 / es};
  float acc = 0.f;
  for (int h = 0; h < 4; ++h) {
    float oh = 0.f;
#pragma unroll
    for (int dd = 0; dd < 10; ++dd) {
      float ev = e[n * 10 + dd];
      float v = Zt[((long)h * 512 + n) * 80 + dd * 8 + b] + fb[h * 10 + dd];
      oh = fmaf(ev, v, oh);
    }
    acc = fmaf(mixv[h], oh, acc);
  }
  g[b * 512 + n] = acc;
}

// ---------- head ----------
__global__ __launch_bounds__(256) void head_kernel(
    const float* __restrict__ g, const float* __restrict__ hw,
    const float* __restrict__ hb, float* __restrict__ out) {
  __shared__ float red[4];
  int b = blockIdx.x, tid = threadIdx.x;
  float w0 = hw[tid], w1 = hw[tid + 256];
  float v = g[b * 512 + tid] * w0 + g[b * 512 + tid + 256] * w1;
  float q = w0 * w0 + w1 * w1;
  float mu = blk_sum4(v, red);
  float s2 = blk_sum4(q, red);
  if (tid == 0) {
    out[b] = mu + hb[0];
    out[8 + b] = logf(1e-6f * s2 + 1e-6f);
  }
}

extern "C" void kernel_launch(void* const* d_in, const int* in_sizes, int n_in,
                              void* d_out, int out_size, void* d_ws, size_t ws_size,
                              hipStream_t stream) {
  (void)in_sizes; (void)n_in; (void)out_size; (void)ws_size;
  const float* x0    = (const float*)d_in[0];
  const float* in_w  = (const float*)d_in[1];
  const float* cw    = (const float*)d_in[2];
  const float* cb    = (const float*)d_in[3];
  const float* pw    = (const float*)d_in[4];
  const float* dtw   = (const float*)d_in[5];
  const float* dtb   = (const float*)d_in[6];
  const float* Alog  = (const float*)d_in[7];
  const float* Dpar  = (const float*)d_in[8];
  const float* ow    = (const float*)d_in[9];
  const float* l1g   = (const float*)d_in[10];
  const float* l1b   = (const float*)d_in[11];
  const float* fw1   = (const float*)d_in[12];
  const float* fb1   = (const float*)d_in[13];
  const float* fw2   = (const float*)d_in[14];
  const float* fb2   = (const float*)d_in[15];
  const float* l2g   = (const float*)d_in[16];
  const float* l2b   = (const float*)d_in[17];
  const float* emb   = (const float*)d_in[18];
  const float* psi   = (const float*)d_in[19];
  const float* Wq    = (const float*)d_in[20];
  const float* Wk    = (const float*)d_in[21];
  const float* aal   = (const float*)d_in[22];
  const float* Fw    = (const float*)d_in[23];
  const float* fbv   = (const float*)d_in[24];
  const float* hmix  = (const float*)d_in[25];
  const float* hw    = (const float*)d_in[26];
  const float* hb    = (const float*)d_in[27];
  float* out = (float*)d_out;

  float* ws = (float*)d_ws;
  float* xA   = ws;                 // 4194304
  float* xB   = xA + 4194304;       // 4194304
  float* scr  = xB + 4194304;       // round scratch / magac alias
  float* xr   = scr;                // 2097152
  float* Bm   = xr + 2097152;       // 1048576
  float* Cm   = Bm + 1048576;       // 1048576
  float* xpT  = Cm + 1048576;       // 1048576
  float* dlT  = xpT + 1048576;      // 1048576
  float* sigT = dlT + 1048576;      // 1048576
  float* ycat = sigT + 1048576;     // 1048576
  float* Sin  = ycat + 1048576;     // 1048576
  // Aprod/Send alias xr (dead after convproj)
  float* Aprod = xr;                // 1048576
  float* Send  = xr + 1048576;      // 1048576
  // magac aliases (round scratch dead by then)
  float* Qb    = scr;               // 20480
  float* Kb    = Qb + 20480;        // 20480
  float* Aef   = Kb + 20480;        // 1048576
  float* DbufP = Aef + 1048576;     // 2621440
  float* X3    = DbufP + 2621440;   // 163840
  float* X2s   = X3 + 163840;       // 163840
  float* X13   = X2s + 163840;      // 163840
  float* X02   = X13 + 163840;      // 163840
  float* Z2    = X02 + 163840;      // 163840
  float* Z1    = Z2 + 163840;       // 163840
  float* Zt    = Z1 + 163840;       // 163840
  float* gb    = Zt + 163840;       // 4096

  const float* xin = x0;
  float* bufs[3] = {xA, xB, xA};
  for (int i = 0; i < 3; ++i) {
    float* xout = bufs[i];
    gemm_f32<<<dim3(2, 128, 2), 256, 0, stream>>>(
        xin, 0, in_w + (long)i * 131072, 65536, xin, 0, xr, 1048576, 0,
        8192, 128, 512, 512, 128, 0, 128, 1.f, 0.f, 1);
    convproj<<<dim3(512, 2), 256, 0, stream>>>(
        xr, cw + i * 384, cb + i * 128, pw + i * 16896, dtw + i * 512,
        dtb + i * 128, Bm, Cm, xpT, dlT, sigT);
    scan_p1<<<dim3(64, 8, 8), 256, 0, stream>>>(
        dlT, xpT, Bm, Alog + i * 8192, Aprod, Send);
    scan_p2<<<dim3(64, 8, 2), 64, 0, stream>>>(Aprod, Send, Sin);
    scan_p3<<<dim3(64, 8, 32), 64, 0, stream>>>(
        dlT, xpT, sigT, Bm, Cm, Alog + i * 8192, Dpar + i * 128, Sin, ycat);
    gemm_f32<<<dim3(8, 128, 1), 256, 0, stream>>>(
        ycat, 0, ow + (long)i * 65536, 0, xin, 0, xout, 0, 0,
        8192, 512, 128, 128, 512, 512, 512, 1.f, 1.f, 1);
    ln_ffn_ln<<<2048, 256, 0, stream>>>(
        xout, l1g + i * 512, l1b + i * 512, fw1 + i * 16384, fb1 + i * 32,
        fw2 + i * 16384, fb2 + i * 512, l2g + i * 512, l2b + i * 512);
    xin = xout;
  }
  // ---- MAGAC (final x in xA) ----
  qk_kernel<<<512, 64, 0, stream>>>(emb, Wq, Wk, Qb, Kb);
  aeff_kernel<<<dim3(512, 4), 256, 0, stream>>>(emb, Qb, Kb, psi, aal, Aef);
  gemm_f32<<<dim3(8, 3, 32), 256, 0, stream>>>(
      Fw, 0, xA, 524288, Fw, 0, DbufP, 81920, 655360,
      160, 512, 256, 1024, 512, 0, 512, 1.f, 0.f, 4);
  xpose_kernel<<<640, 256, 0, stream>>>(DbufP, X3, X2s, X13, X02);
  gemm_f32<<<dim3(2, 8, 4), 256, 0, stream>>>(
      Aef, 262144, X3, 40960, X2s, 40960, Z2, 40960, 0,
      512, 80, 512, 512, 80, 80, 80, 4.f, 2.f, 1);
  gemm_f32<<<dim3(2, 8, 4), 256, 0, stream>>>(
      Aef, 262144, Z2, 40960, X13, 40960, Z1, 40960, 0,
      512, 80, 512, 512, 80, 80, 80, 1.f, 1.f, 1);
  gemm_f32<<<dim3(2, 8, 4), 256, 0, stream>>>(
      Aef, 262144, Z1, 40960, X02, 40960, Zt, 40960, 0,
      512, 80, 512, 512, 80, 80, 80, 1.f, 1.f, 1);
  outh_kernel<<<16, 256, 0, stream>>>(emb, fbv, Zt, hmix, gb);
  head_kernel<<<8, 256, 0, stream>>>(gb, hw, hb, out);
}

// Round 18
// 698.456 us; speedup vs baseline: 1.2324x; 1.2324x over previous
//
#include <hip/hip_runtime.h>
#include <math.h>

#define SEQL 1024
#define NB 8
#define DMOD 512

// ---------- reduction helpers (256-thread blocks, 4 waves) ----------
__device__ __forceinline__ float blk_sum4(float v, volatile float* sb) {
#pragma unroll
  for (int off = 32; off; off >>= 1) v += __shfl_xor(v, off, 64);
  int lid = threadIdx.x & 63, wid = threadIdx.x >> 6;
  if (lid == 0) sb[wid] = v;
  __syncthreads();
  float t = sb[0] + sb[1] + sb[2] + sb[3];
  __syncthreads();
  return t;
}
__device__ __forceinline__ float blk_max4(float v, volatile float* sb) {
#pragma unroll
  for (int off = 32; off; off >>= 1) v = fmaxf(v, __shfl_xor(v, off, 64));
  int lid = threadIdx.x & 63, wid = threadIdx.x >> 6;
  if (lid == 0) sb[wid] = v;
  __syncthreads();
  float t = fmaxf(fmaxf(sb[0], sb[1]), fmaxf(sb[2], sb[3]));
  __syncthreads();
  return t;
}

// ---------- generic f32 GEMM, 64x64 tile, 256 threads (R16 measured best) ----------
__global__ __launch_bounds__(256) void gemm_f32(
    const float* __restrict__ A, long aStr,
    const float* __restrict__ B, long bStr,
    const float* __restrict__ Dm, long dStr,
    float* __restrict__ C, long cStr, long cChunkStr,
    int M, int N, int K, int lda, int ldb, int ldd, int ldc,
    float alpha, float beta, int kchunks) {
  __shared__ float As[2][16][68];
  __shared__ float Bs[2][16][64];
  const int zz = blockIdx.z;
  const int zb = zz / kchunks, kc = zz % kchunks;
  A += (long)zb * aStr + (long)kc * K;
  B += (long)zb * bStr + (long)kc * K * ldb;
  Dm += (long)zb * dStr;
  C += (long)zb * cStr + (long)kc * cChunkStr;
  const int tid = threadIdx.x;
  const int m0 = blockIdx.y * 64, n0 = blockIdx.x * 64;
  const int tx = tid & 15, ty = tid >> 4;
  const int arow = tid >> 2, acol = (tid & 3) << 2;
  const int brow = tid >> 4, bcol = (tid & 15) << 2;
  const bool aOk = (m0 + arow < M);
  const float* Aptr = A + (long)(m0 + arow) * lda + acol;
  const float* Bptr = B + (long)brow * ldb;
  const int bc = n0 + bcol;
  const int kIters = K >> 4;
  float acc[4][4] = {};

  auto loadB = [&](int it) {
    const float* Bk = Bptr + (long)it * 16 * ldb;
    float4 r;
    if (bc + 3 < N) r = *(const float4*)(Bk + bc);
    else {
      r.x = (bc + 0 < N) ? Bk[bc + 0] : 0.f;
      r.y = (bc + 1 < N) ? Bk[bc + 1] : 0.f;
      r.z = (bc + 2 < N) ? Bk[bc + 2] : 0.f;
      r.w = (bc + 3 < N) ? Bk[bc + 3] : 0.f;
    }
    return r;
  };

  float4 av = make_float4(0.f, 0.f, 0.f, 0.f);
  if (aOk) av = *(const float4*)(Aptr);
  float4 bv = loadB(0);
  As[0][acol + 0][arow] = av.x; As[0][acol + 1][arow] = av.y;
  As[0][acol + 2][arow] = av.z; As[0][acol + 3][arow] = av.w;
  *(float4*)&Bs[0][brow][bcol] = bv;

  for (int it = 0; it < kIters; ++it) {
    const int cur = it & 1;
    __syncthreads();
    const bool more = (it + 1 < kIters);
    if (more) {
      if (aOk) av = *(const float4*)(Aptr + (it + 1) * 16);
      bv = loadB(it + 1);
    }
#pragma unroll
    for (int kk = 0; kk < 16; ++kk) {
      float4 aq = *(const float4*)&As[cur][kk][ty << 2];
      float4 bq = *(const float4*)&Bs[cur][kk][tx << 2];
      float aa[4] = {aq.x, aq.y, aq.z, aq.w};
      float bb[4] = {bq.x, bq.y, bq.z, bq.w};
#pragma unroll
      for (int i = 0; i < 4; ++i)
#pragma unroll
        for (int j = 0; j < 4; ++j) acc[i][j] = fmaf(aa[i], bb[j], acc[i][j]);
    }
    if (more) {
      const int nxt = cur ^ 1;
      As[nxt][acol + 0][arow] = av.x; As[nxt][acol + 1][arow] = av.y;
      As[nxt][acol + 2][arow] = av.z; As[nxt][acol + 3][arow] = av.w;
      *(float4*)&Bs[nxt][brow][bcol] = bv;
    }
  }
#pragma unroll
  for (int i = 0; i < 4; ++i) {
    int row = m0 + (ty << 2) + i;
    if (row >= M) continue;
#pragma unroll
    for (int j = 0; j < 4; ++j) {
      int col = n0 + (tx << 2) + j;
      if (col >= N) continue;
      float v = alpha * acc[i][j];
      if (beta != 0.f) v += beta * Dm[(long)row * ldd + col];
      C[(long)row * ldc + col] = v;
    }
  }
}

// ---------- fused conv + SiLU + x-proj + dt-proj (4 tokens/wave, pw in LDS) ----------
__global__ __launch_bounds__(256) void convproj(
    const float* __restrict__ xr, const float* __restrict__ cw,
    const float* __restrict__ cb, const float* __restrict__ pw,
    const float* __restrict__ dw, const float* __restrict__ db,
    float* __restrict__ Bm, float* __restrict__ Cm,
    float* __restrict__ xpT, float* __restrict__ dlT, float* __restrict__ sigT) {
  __shared__ float sWp[8448];      // per-dir x-proj weights (33 KB)
  int dir = blockIdx.y;
  int L = blockIdx.x;              // 0..511
  int r = L & 7, q = L >> 3;       // XCD class r = batch b
  int wv = threadIdx.x >> 6, e = threadIdx.x & 63;
  int b = r;
  int t0 = q * 16 + wv * 4;        // 4 consecutive tokens per wave
  long tokbase = (long)b * 1024;
  const float* x0p = xr + (long)dir * 1048576;
  const float* wp = pw + dir * 8448;
  for (int i = threadIdx.x; i < 8448; i += 256) sWp[i] = wp[i];
  int base = dir ? t0 : t0 - 2;
  float X[6];
#pragma unroll
  for (int j = 0; j < 6; ++j) {
    int tt = base + j;
    X[j] = (tt >= 0 && tt <= 1023) ? x0p[(tokbase + tt) * 128 + e] : 0.f;
  }
  const float* w = cw + dir * 192;
  float w0 = w[e * 3 + 0], w1 = w[e * 3 + 1], w2 = w[e * 3 + 2];
  float wLo = dir ? w2 : w0;
  float wHi = dir ? w0 : w2;
  float cbv = cb[dir * 64 + e];
  float xpv[4], sg[4];
#pragma unroll
  for (int i = 0; i < 4; ++i) {
    float acc = cbv + wLo * X[i] + w1 * X[i + 1] + wHi * X[i + 2];
    xpv[i] = acc / (1.f + __expf(-acc));
    float res = x0p[(tokbase + t0 + i) * 128 + 64 + e];
    sg[i] = 1.f / (1.f + __expf(-res));
  }
  __syncthreads();
  float aB[4] = {}, aC[4] = {}, aD[4] = {};
  for (int k = 0; k < 64; ++k) {
    const float* wr = sWp + k * 132;
    float wB = wr[4 + e], wC = wr[68 + e], wD = wr[e & 3];
#pragma unroll
    for (int i = 0; i < 4; ++i) {
      float xk = __shfl(xpv[i], k, 64);
      aB[i] = fmaf(xk, wB, aB[i]);
      aC[i] = fmaf(xk, wC, aC[i]);
      aD[i] = fmaf(xk, wD, aD[i]);
    }
  }
  long ob = (long)dir * 524288 + (tokbase + t0) * 64 + e;
#pragma unroll
  for (int i = 0; i < 4; ++i) {
    Bm[ob + (long)i * 64] = aB[i];
    Cm[ob + (long)i * 64] = aC[i];
  }
  const float* dwp = dw + dir * 256;
  float dbv = db[dir * 64 + e];
  float dl[4];
#pragma unroll
  for (int i = 0; i < 4; ++i) {
    float dv = dbv;
#pragma unroll
    for (int rr = 0; rr < 4; ++rr) dv = fmaf(__shfl(aD[i], rr, 64), dwp[rr * 64 + e], dv);
    dl[i] = fmaxf(dv, 0.f) + log1pf(__expf(-fabsf(dv)));
  }
  long tb2 = (long)dir * 524288 + (long)b * 65536 + (long)e * 1024 + t0;
  *(float4*)&xpT[tb2] = make_float4(xpv[0], xpv[1], xpv[2], xpv[3]);
  *(float4*)&dlT[tb2] = make_float4(dl[0], dl[1], dl[2], dl[3]);
  *(float4*)&sigT[tb2] = make_float4(sg[0], sg[1], sg[2], sg[3]);
}

// ---------- XCD-aware remap, 4 waves/block (scan_p1) ----------
__device__ __forceinline__ void remap4w(int wv, int& d, int& b, int& dir, int& c) {
  int L = blockIdx.x + 64 * (blockIdx.y + 8 * blockIdx.z);  // grid (64,8,8) = 4096
  int r = L & 7, s = L >> 3;
  int u = s * 4 + wv;            // 0..2047 within class r
  d = u & 63;
  int T = (u >> 6) * 8 + r;      // 0..255
  b = T >> 5;
  dir = (T >> 4) & 1;
  c = T & 15;
}

// ---------- XCD-aware remap, 1-wave blocks (scan_p3) ----------
__device__ __forceinline__ void scan_remap(int& d, int& b, int& dir, int& c) {
  int L = blockIdx.x + 64 * (blockIdx.y + 8 * blockIdx.z);  // grid (64,8,32)
  int r = L & 7, q = L >> 3;
  d = q & 63;
  int T = (q >> 6) * 8 + r;  // 0..255
  b = T >> 5;
  dir = (T >> 4) & 1;
  c = T & 15;
}

// ---------- chunked parallel selective scan ----------
// p1: 4 waves/block, register-prefetched B sub-blocks
__global__ __launch_bounds__(256) void scan_p1(
    const float* __restrict__ dlT, const float* __restrict__ xpT,
    const float* __restrict__ Bm, const float* __restrict__ Alog,
    float* __restrict__ Aprod, float* __restrict__ Send) {
  int wv = threadIdx.x >> 6, n = threadIdx.x & 63;
  int d, b, dir, c;
  remap4w(wv, d, b, dir, c);
  long tbase = (long)dir * 524288 + (long)b * 65536 + (long)d * 1024;
  int t0 = c * 64;
  float a_dn = -__expf(Alog[dir * 4096 + d * 64 + n]);
  int tg0 = dir ? (1023 - t0) : t0;
  long bstep = dir ? -64 : 64;
  const float* bp = Bm + (long)dir * 524288 + ((long)b * 1024 + tg0) * 64 + n;
  const float* dlrow = dlT + tbase;
  const float* xprow = xpT + tbase;
  float s = 0.f, ap0 = 1.f, ap1 = 1.f;
  float bcur[16];
#pragma unroll
  for (int k = 0; k < 16; ++k) bcur[k] = bp[(long)k * bstep];
  bp += 16 * bstep;
  for (int sb = 0; sb < 4; ++sb) {
    float sa[16], su[16];
#pragma unroll
    for (int k = 0; k < 16; ++k) {
      int tl = t0 + sb * 16 + k;
      int tg = dir ? 1023 - tl : tl;
      float dv = dlrow[tg];
      sa[k] = dv;
      su[k] = dv * xprow[tg];
    }
    float bnxt[16];
    if (sb < 3) {
#pragma unroll
      for (int k = 0; k < 16; ++k) bnxt[k] = bp[(long)k * bstep];
      bp += 16 * bstep;
    }
#pragma unroll
    for (int k = 0; k < 16; ++k) {
      float a = __expf(sa[k] * a_dn);
      if (k & 1) ap1 *= a; else ap0 *= a;
      s = fmaf(a, s, su[k] * bcur[k]);
    }
    if (sb < 3) {
#pragma unroll
      for (int k = 0; k < 16; ++k) bcur[k] = bnxt[k];
    }
  }
  long sidx = ((long)((dir * 8 + b) * 64 + d)) * 1024 + c * 64 + n;
  Aprod[sidx] = ap0 * ap1;
  Send[sidx] = s;
}

__global__ __launch_bounds__(64) void scan_p2(
    const float* __restrict__ Aprod, const float* __restrict__ Send,
    float* __restrict__ Sin) {
  int d = blockIdx.x, b = blockIdx.y, dir = blockIdx.z;
  int n = threadIdx.x;
  long base = ((long)((dir * 8 + b) * 64 + d)) * 1024;
  float apv[16], sev[16];
#pragma unroll
  for (int c = 0; c < 16; ++c) {
    apv[c] = Aprod[base + c * 64 + n];
    sev[c] = Send[base + c * 64 + n];
  }
  float s = 0.f;
#pragma unroll
  for (int c = 0; c < 16; ++c) {
    Sin[base + c * 64 + n] = s;
    s = fmaf(apv[c], s, sev[c]);
  }
}

// p3: 1-wave blocks + register-prefetched B/C
__global__ __launch_bounds__(64) void scan_p3(
    const float* __restrict__ dlT, const float* __restrict__ xpT,
    const float* __restrict__ sigT, const float* __restrict__ Bm,
    const float* __restrict__ Cm, const float* __restrict__ Alog,
    const float* __restrict__ Dp, const float* __restrict__ Sin,
    float* __restrict__ ycat) {
  __shared__ float sP[16 * 65];
  int d, b, dir, c;
  scan_remap(d, b, dir, c);
  int n = threadIdx.x;
  long tbase = (long)dir * 524288 + (long)b * 65536 + (long)d * 1024;
  int t0 = c * 64;
  int tln = t0 + n;
  int tgn = dir ? 1023 - tln : tln;
  float xp_l = xpT[tbase + tgn];
  float sg_l = sigT[tbase + tgn];
  float a_dn = -__expf(Alog[dir * 4096 + d * 64 + n]);
  float dpd = Dp[dir * 64 + d];
  int tg0 = dir ? (1023 - t0) : t0;
  long bstep = dir ? -64 : 64;
  long boff = (long)dir * 524288 + ((long)b * 1024 + tg0) * 64 + n;
  const float* bp = Bm + boff;
  const float* cp = Cm + boff;
  long sidx = ((long)((dir * 8 + b) * 64 + d)) * 1024 + c * 64 + n;
  float s = Sin[sidx];
  int r4 = n >> 2, q4 = n & 3;
  const float* dlrow = dlT + tbase;
  const float* xprow = xpT + tbase;
  float bcur[16], ccur[16];
#pragma unroll
  for (int k = 0; k < 16; ++k) {
    bcur[k] = bp[(long)k * bstep];
    ccur[k] = cp[(long)k * bstep];
  }
  bp += 16 * bstep; cp += 16 * bstep;
  for (int ph = 0; ph < 4; ++ph) {
    float sa[16], su[16];
#pragma unroll
    for (int k = 0; k < 16; ++k) {
      int tl = t0 + ph * 16 + k;
      int tg = dir ? 1023 - tl : tl;
      float dv = dlrow[tg];
      sa[k] = dv;
      su[k] = dv * xprow[tg];
    }
    float bnxt[16], cnxt[16];
    if (ph < 3) {
#pragma unroll
      for (int k = 0; k < 16; ++k) {
        bnxt[k] = bp[(long)k * bstep];
        cnxt[k] = cp[(long)k * bstep];
      }
      bp += 16 * bstep; cp += 16 * bstep;
    }
#pragma unroll
    for (int k = 0; k < 16; ++k) {
      float a = __expf(sa[k] * a_dn);
      s = fmaf(a, s, su[k] * bcur[k]);
      sP[k * 65 + n] = s * ccur[k];
    }
    __syncthreads();
    float p = 0.f;
#pragma unroll
    for (int k = 0; k < 16; ++k) p += sP[r4 * 65 + q4 * 16 + k];
    p += __shfl_xor(p, 1, 64);
    p += __shfl_xor(p, 2, 64);
    int stl = ph * 16 + r4;
    float xpv_r = __shfl(xp_l, stl, 64);
    float sgv = __shfl(sg_l, stl, 64);
    if (q4 == 0) {
      int tl = t0 + stl;
      int tg = dir ? 1023 - tl : tl;
      ycat[((long)b * 1024 + tg) * 128 + dir * 64 + d] = (p + xpv_r * dpd) * sgv;
    }
    __syncthreads();
    if (ph < 3) {
#pragma unroll
      for (int k = 0; k < 16; ++k) { bcur[k] = bnxt[k]; ccur[k] = cnxt[k]; }
    }
  }
}

// ---------- fused LN1 + FFN(512->32->512) + LN2, 4 tokens per block ----------
__global__ __launch_bounds__(256) void ln_ffn_ln(
    float* __restrict__ x, const float* __restrict__ g1, const float* __restrict__ b1v,
    const float* __restrict__ w1, const float* __restrict__ bb1,
    const float* __restrict__ w2, const float* __restrict__ bb2,
    const float* __restrict__ g2, const float* __restrict__ b2v) {
  __shared__ float ybuf[4][512];
  __shared__ float rbuf[4][256];
  __shared__ float zbuf[4][32];
  __shared__ float red4[32];
  int tid = threadIdx.x;
  int lid = tid & 63, wid = tid >> 6;
  float* row0 = x + (long)blockIdx.x * 2048;
  float a[4], bb[4], s[4], q[4];
#pragma unroll
  for (int t = 0; t < 4; ++t) {
    a[t] = row0[t * 512 + tid];
    bb[t] = row0[t * 512 + tid + 256];
    s[t] = a[t] + bb[t];
    q[t] = a[t] * a[t] + bb[t] * bb[t];
  }
#pragma unroll
  for (int off = 32; off; off >>= 1) {
#pragma unroll
    for (int t = 0; t < 4; ++t) {
      s[t] += __shfl_xor(s[t], off, 64);
      q[t] += __shfl_xor(q[t], off, 64);
    }
  }
  if (lid == 0) {
#pragma unroll
    for (int t = 0; t < 4; ++t) {
      red4[wid * 8 + t] = s[t];
      red4[wid * 8 + 4 + t] = q[t];
    }
  }
  __syncthreads();
  float g1a = g1[tid], g1b = g1[tid + 256];
  float b1a = b1v[tid], b1b = b1v[tid + 256];
  float ya[4], yb[4];
#pragma unroll
  for (int t = 0; t < 4; ++t) {
    float S = red4[t] + red4[8 + t] + red4[16 + t] + red4[24 + t];
    float Q = red4[4 + t] + red4[12 + t] + red4[20 + t] + red4[28 + t];
    float mu = S * (1.f / 512.f);
    float rs = 1.f / sqrtf(Q * (1.f / 512.f) - mu * mu + 1e-5f);
    ya[t] = (a[t] - mu) * rs * g1a + b1a;
    yb[t] = (bb[t] - mu) * rs * g1b + b1b;
    ybuf[t][tid] = ya[t];
    ybuf[t][tid + 256] = yb[t];
  }
  __syncthreads();
  int u = tid & 31, seg = tid >> 5;
  int k0 = seg * 64;
  float p[4] = {};
#pragma unroll
  for (int k = 0; k < 64; k += 4) {
    float w1v0 = w1[(k0 + k + 0) * 32 + u];
    float w1v1 = w1[(k0 + k + 1) * 32 + u];
    float w1v2 = w1[(k0 + k + 2) * 32 + u];
    float w1v3 = w1[(k0 + k + 3) * 32 + u];
#pragma unroll
    for (int t = 0; t < 4; ++t) {
      float4 yv = *(const float4*)&ybuf[t][k0 + k];
      p[t] = fmaf(yv.w, w1v3, fmaf(yv.z, w1v2, fmaf(yv.y, w1v1, fmaf(yv.x, w1v0, p[t]))));
    }
  }
#pragma unroll
  for (int t = 0; t < 4; ++t) rbuf[t][seg * 32 + u] = p[t];
  __syncthreads();
  if (tid < 128) {
    int t = tid >> 5, uu = tid & 31;
    float zv = bb1[uu];
#pragma unroll
    for (int sg = 0; sg < 8; ++sg) zv += rbuf[t][sg * 32 + uu];
    zbuf[t][uu] = fmaxf(zv, 0.f);
  }
  __syncthreads();
  float bb2a = bb2[tid], bb2b = bb2[tid + 256];
  float ha[4], hb[4];
#pragma unroll
  for (int t = 0; t < 4; ++t) { ha[t] = ya[t] + bb2a; hb[t] = yb[t] + bb2b; }
#pragma unroll
  for (int uu = 0; uu < 32; ++uu) {
    float wa = w2[uu * 512 + tid], wb = w2[uu * 512 + tid + 256];
#pragma unroll
    for (int t = 0; t < 4; ++t) {
      float zv = zbuf[t][uu];
      ha[t] = fmaf(zv, wa, ha[t]);
      hb[t] = fmaf(zv, wb, hb[t]);
    }
  }
#pragma unroll
  for (int t = 0; t < 4; ++t) {
    s[t] = ha[t] + hb[t];
    q[t] = ha[t] * ha[t] + hb[t] * hb[t];
  }
#pragma unroll
  for (int off = 32; off; off >>= 1) {
#pragma unroll
    for (int t = 0; t < 4; ++t) {
      s[t] += __shfl_xor(s[t], off, 64);
      q[t] += __shfl_xor(q[t], off, 64);
    }
  }
  __syncthreads();
  if (lid == 0) {
#pragma unroll
    for (int t = 0; t < 4; ++t) {
      red4[wid * 8 + t] = s[t];
      red4[wid * 8 + 4 + t] = q[t];
    }
  }
  __syncthreads();
  float g2a = g2[tid], g2b = g2[tid + 256];
  float b2a = b2v[tid], b2b = b2v[tid + 256];
#pragma unroll
  for (int t = 0; t < 4; ++t) {
    float S = red4[t] + red4[8 + t] + red4[16 + t] + red4[24 + t];
    float Q = red4[4 + t] + red4[12 + t] + red4[20 + t] + red4[28 + t];
    float mu = S * (1.f / 512.f);
    float rs = 1.f / sqrtf(Q * (1.f / 512.f) - mu * mu + 1e-5f);
    row0[t * 512 + tid] = (ha[t] - mu) * rs * g2a + b2a;
    row0[t * 512 + tid + 256] = (hb[t] - mu) * rs * g2b + b2b;
  }
}

// ---------- MAGAC: Q/K projections ----------
__global__ __launch_bounds__(64) void qk_kernel(
    const float* __restrict__ e, const float* __restrict__ Wq,
    const float* __restrict__ Wk, float* __restrict__ Qb, float* __restrict__ Kb) {
  int n = blockIdx.x, j = threadIdx.x;
  __shared__ float en[10];
  if (j < 10) en[j] = e[n * 10 + j];
  __syncthreads();
  if (j < 40) {
    float q = 0.f, k = 0.f;
#pragma unroll
    for (int dd = 0; dd < 10; ++dd) {
      q = fmaf(en[dd], Wq[dd * 40 + j], q);
      k = fmaf(en[dd], Wk[dd * 40 + j], k);
    }
    Qb[n * 40 + j] = q;
    Kb[n * 40 + j] = k;
  }
}

// ---------- MAGAC: A_eff row (dual softmax) ----------
__global__ __launch_bounds__(256) void aeff_kernel(
    const float* __restrict__ e, const float* __restrict__ Qb,
    const float* __restrict__ Kb, const float* __restrict__ psi_p,
    const float* __restrict__ alpha_p, float* __restrict__ Aef) {
  int n = blockIdx.x, h = blockIdx.y, tid = threadIdx.x;
  __shared__ float s_at[512];
  __shared__ float s_bs[512];
  __shared__ float qn[10];
  __shared__ float en[10];
  __shared__ float red[4];
  if (tid < 10) { qn[tid] = Qb[n * 40 + h * 10 + tid]; en[tid] = e[n * 10 + tid]; }
  __syncthreads();
  float psi = psi_p[0];
  float alpha = 1.f / (1.f + __expf(-alpha_p[0]));
  const float isq = 0.3162277660168379f;
  for (int m = tid; m < 512; m += 256) {
    float sc = 0.f, d2 = 0.f;
#pragma unroll
    for (int dd = 0; dd < 10; ++dd) {
      sc = fmaf(qn[dd], Kb[m * 40 + h * 10 + dd], sc);
      float df = en[dd] - e[m * 10 + dd];
      d2 = fmaf(df, df, d2);
    }
    s_at[m] = sc * isq;
    s_bs[m] = __expf(-psi * d2);
  }
  __syncthreads();
  float m1 = -1e30f, m2 = -1e30f;
  for (int m = tid; m < 512; m += 256) { m1 = fmaxf(m1, s_at[m]); m2 = fmaxf(m2, s_bs[m]); }
  m1 = blk_max4(m1, red);
  m2 = blk_max4(m2, red);
  float e1 = 0.f, e2 = 0.f;
  for (int m = tid; m < 512; m += 256) {
    float a = __expf(s_at[m] - m1); s_at[m] = a; e1 += a;
    float bq = __expf(s_bs[m] - m2); s_bs[m] = bq; e2 += bq;
  }
  e1 = blk_sum4(e1, red);
  e2 = blk_sum4(e2, red);
  float r1 = (1.f - alpha) / e1, r2 = alpha / e2;
  float* outp = Aef + (long)h * 262144 + (long)n * 512;
  for (int m = tid; m < 512; m += 256) outp[m] = r2 * s_bs[m] + r1 * s_at[m];
}

// ---------- sum Dbuf K-partials + transpose into Horner operand layouts ----------
__global__ void xpose_kernel(const float* __restrict__ DbufP,
                             float* __restrict__ X3, float* __restrict__ X2s,
                             float* __restrict__ X13, float* __restrict__ X02) {
  int idx = blockIdx.x * 256 + threadIdx.x;  // 163840
  if (idx >= 163840) return;
  int c = idx % 80;
  int m = (idx / 80) % 512;
  int h = idx / 40960;
  int d = c >> 3, b = c & 7;
  long base = (long)(b * 160 + h * 40 + d * 4) * 512 + m;
  float k0 = 0.f, k1 = 0.f, k2 = 0.f, k3 = 0.f;
#pragma unroll
  for (int p = 0; p < 4; ++p) {
    const float* Dp_ = DbufP + (long)p * 655360;
    k0 += Dp_[base];
    k1 += Dp_[base + 512];
    k2 += Dp_[base + 1024];
    k3 += Dp_[base + 1536];
  }
  X3[idx] = k3;
  X2s[idx] = k2;
  X13[idx] = k1 - 3.f * k3;
  X02[idx] = k0 - k2;
}

// ---------- final contraction ----------
__global__ void outh_kernel(const float* __restrict__ e, const float* __restrict__ fb,
                            const float* __restrict__ Zt, const float* __restrict__ hm,
                            float* __restrict__ g) {
  int idx = blockIdx.x * 256 + threadIdx.x;  // 4096
  if (idx >= 4096) return;
  int n = idx & 511, b = idx >> 9;
  float h0 = hm[0], h1 = hm[1], h2 = hm[2], h3 = hm[3];
  float mx = fmaxf(fmaxf(h0, h1), fmaxf(h2, h3));
  float x0 = __expf(h0 - mx), x1 = __expf(h1 - mx), x2 = __expf(h2 - mx), x3 = __expf(h3 - mx);
  float es = x0 + x1 + x2 + x3;
  float mixv[4] = {x0 / es, x1 / es, x2 / es, x3 / es};
  float acc = 0.f;
  for (int h = 0; h < 4; ++h) {
    float oh = 0.f;
#pragma unroll
    for (int dd = 0; dd < 10; ++dd) {
      float ev = e[n * 10 + dd];
      float v = Zt[((long)h * 512 + n) * 80 + dd * 8 + b] + fb[h * 10 + dd];
      oh = fmaf(ev, v, oh);
    }
    acc = fmaf(mixv[h], oh, acc);
  }
  g[b * 512 + n] = acc;
}

// ---------- head ----------
__global__ __launch_bounds__(256) void head_kernel(
    const float* __restrict__ g, const float* __restrict__ hw,
    const float* __restrict__ hb, float* __restrict__ out) {
  __shared__ float red[4];
  int b = blockIdx.x, tid = threadIdx.x;
  float w0 = hw[tid], w1 = hw[tid + 256];
  float v = g[b * 512 + tid] * w0 + g[b * 512 + tid + 256] * w1;
  float q = w0 * w0 + w1 * w1;
  float mu = blk_sum4(v, red);
  float s2 = blk_sum4(q, red);
  if (tid == 0) {
    out[b] = mu + hb[0];
    out[8 + b] = logf(1e-6f * s2 + 1e-6f);
  }
}

extern "C" void kernel_launch(void* const* d_in, const int* in_sizes, int n_in,
                              void* d_out, int out_size, void* d_ws, size_t ws_size,
                              hipStream_t stream) {
  (void)in_sizes; (void)n_in; (void)out_size; (void)ws_size;
  const float* x0    = (const float*)d_in[0];
  const float* in_w  = (const float*)d_in[1];
  const float* cw    = (const float*)d_in[2];
  const float* cb    = (const float*)d_in[3];
  const float* pw    = (const float*)d_in[4];
  const float* dtw   = (const float*)d_in[5];
  const float* dtb   = (const float*)d_in[6];
  const float* Alog  = (const float*)d_in[7];
  const float* Dpar  = (const float*)d_in[8];
  const float* ow    = (const float*)d_in[9];
  const float* l1g   = (const float*)d_in[10];
  const float* l1b   = (const float*)d_in[11];
  const float* fw1   = (const float*)d_in[12];
  const float* fb1   = (const float*)d_in[13];
  const float* fw2   = (const float*)d_in[14];
  const float* fb2   = (const float*)d_in[15];
  const float* l2g   = (const float*)d_in[16];
  const float* l2b   = (const float*)d_in[17];
  const float* emb   = (const float*)d_in[18];
  const float* psi   = (const float*)d_in[19];
  const float* Wq    = (const float*)d_in[20];
  const float* Wk    = (const float*)d_in[21];
  const float* aal   = (const float*)d_in[22];
  const float* Fw    = (const float*)d_in[23];
  const float* fbv   = (const float*)d_in[24];
  const float* hmix  = (const float*)d_in[25];
  const float* hw    = (const float*)d_in[26];
  const float* hb    = (const float*)d_in[27];
  float* out = (float*)d_out;

  float* ws = (float*)d_ws;
  float* xA   = ws;                 // 4194304
  float* xB   = xA + 4194304;       // 4194304
  float* scr  = xB + 4194304;       // round scratch / magac alias
  float* xr   = scr;                // 2097152
  float* Bm   = xr + 2097152;       // 1048576
  float* Cm   = Bm + 1048576;       // 1048576
  float* xpT  = Cm + 1048576;       // 1048576
  float* dlT  = xpT + 1048576;      // 1048576
  float* sigT = dlT + 1048576;      // 1048576
  float* ycat = sigT + 1048576;     // 1048576
  float* Sin  = ycat + 1048576;     // 1048576
  // Aprod/Send alias xr (dead after convproj)
  float* Aprod = xr;                // 1048576
  float* Send  = xr + 1048576;      // 1048576
  // magac aliases (round scratch dead by then)
  float* Qb    = scr;               // 20480
  float* Kb    = Qb + 20480;        // 20480
  float* Aef   = Kb + 20480;        // 1048576
  float* DbufP = Aef + 1048576;     // 2621440
  float* X3    = DbufP + 2621440;   // 163840
  float* X2s   = X3 + 163840;       // 163840
  float* X13   = X2s + 163840;      // 163840
  float* X02   = X13 + 163840;      // 163840
  float* Z2    = X02 + 163840;      // 163840
  float* Z1    = Z2 + 163840;       // 163840
  float* Zt    = Z1 + 163840;       // 163840
  float* gb    = Zt + 163840;       // 4096

  const float* xin = x0;
  float* bufs[3] = {xA, xB, xA};
  for (int i = 0; i < 3; ++i) {
    float* xout = bufs[i];
    gemm_f32<<<dim3(2, 128, 2), 256, 0, stream>>>(
        xin, 0, in_w + (long)i * 131072, 65536, xin, 0, xr, 1048576, 0,
        8192, 128, 512, 512, 128, 0, 128, 1.f, 0.f, 1);
    convproj<<<dim3(512, 2), 256, 0, stream>>>(
        xr, cw + i * 384, cb + i * 128, pw + i * 16896, dtw + i * 512,
        dtb + i * 128, Bm, Cm, xpT, dlT, sigT);
    scan_p1<<<dim3(64, 8, 8), 256, 0, stream>>>(
        dlT, xpT, Bm, Alog + i * 8192, Aprod, Send);
    scan_p2<<<dim3(64, 8, 2), 64, 0, stream>>>(Aprod, Send, Sin);
    scan_p3<<<dim3(64, 8, 32), 64, 0, stream>>>(
        dlT, xpT, sigT, Bm, Cm, Alog + i * 8192, Dpar + i * 128, Sin, ycat);
    gemm_f32<<<dim3(8, 128, 1), 256, 0, stream>>>(
        ycat, 0, ow + (long)i * 65536, 0, xin, 0, xout, 0, 0,
        8192, 512, 128, 128, 512, 512, 512, 1.f, 1.f, 1);
    ln_ffn_ln<<<2048, 256, 0, stream>>>(
        xout, l1g + i * 512, l1b + i * 512, fw1 + i * 16384, fb1 + i * 32,
        fw2 + i * 16384, fb2 + i * 512, l2g + i * 512, l2b + i * 512);
    xin = xout;
  }
  // ---- MAGAC (final x in xA) ----
  qk_kernel<<<512, 64, 0, stream>>>(emb, Wq, Wk, Qb, Kb);
  aeff_kernel<<<dim3(512, 4), 256, 0, stream>>>(emb, Qb, Kb, psi, aal, Aef);
  gemm_f32<<<dim3(8, 3, 32), 256, 0, stream>>>(
      Fw, 0, xA, 524288, Fw, 0, DbufP, 81920, 655360,
      160, 512, 256, 1024, 512, 0, 512, 1.f, 0.f, 4);
  xpose_kernel<<<640, 256, 0, stream>>>(DbufP, X3, X2s, X13, X02);
  gemm_f32<<<dim3(2, 8, 4), 256, 0, stream>>>(
      Aef, 262144, X3, 40960, X2s, 40960, Z2, 40960, 0,
      512, 80, 512, 512, 80, 80, 80, 4.f, 2.f, 1);
  gemm_f32<<<dim3(2, 8, 4), 256, 0, stream>>>(
      Aef, 262144, Z2, 40960, X13, 40960, Z1, 40960, 0,
      512, 80, 512, 512, 80, 80, 80, 1.f, 1.f, 1);
  gemm_f32<<<dim3(2, 8, 4), 256, 0, stream>>>(
      Aef, 262144, Z1, 40960, X02, 40960, Zt, 40960, 0,
      512, 80, 512, 512, 80, 80, 80, 1.f, 1.f, 1);
  outh_kernel<<<16, 256, 0, stream>>>(emb, fbv, Zt, hmix, gb);
  head_kernel<<<8, 256, 0, stream>>>(gb, hw, hb, out);
}